// Round 2
// baseline (1631.524 us; speedup 1.0000x reference)
//
#include <hip/hip_runtime.h>
#include <hip/hip_bf16.h>
#include <stdint.h>

#define HID   1024
#define KD    2048      // reduction dim = 2*HID
#define NK    (KD/64)   // 32 K-tiles of 64
#define BATCH 32
#define SRC   2048

typedef __attribute__((ext_vector_type(4))) float  f32x4;
typedef __attribute__((ext_vector_type(8))) __bf16 bf16x8;
typedef __attribute__((ext_vector_type(4))) __bf16 bf16x4;

// ---------------------------------------------------------------- prep: cast W_e -> bf16 contiguous, zero logits(=d_out)
__global__ __launch_bounds__(256) void prep_w_kernel(const float* __restrict__ attn_w,
                                                     __bf16* __restrict__ wbuf,
                                                     float* __restrict__ out)
{
    int gid = blockIdx.x * 256 + threadIdx.x;          // 0..524287
    int p = gid << 2;                                  // element quad
    int h = p >> 11;                                   // 0..1023
    int e = p & 2047;
    f32x4 w = *(const f32x4*)(attn_w + (size_t)h * 3072 + HID + e);
    bf16x4 o = { (__bf16)w[0], (__bf16)w[1], (__bf16)w[2], (__bf16)w[3] };
    *(bf16x4*)(wbuf + p) = o;
    if (gid < 16384) {                                 // zero all 65536 logits
        f32x4 z = {0.f, 0.f, 0.f, 0.f};
        ((f32x4*)out)[gid] = z;
    }
}

// ---------------------------------------------------------------- prep: hb[b][h] = hidden@w_h.T + bias  (f32, exact)
// 4-way split-K: thread (h,b,kc) sums 256 elems; shfl-reduce over kc. 512 blocks.
__global__ __launch_bounds__(256) void prep_h_kernel(const float* __restrict__ hidden,
                                                     const float* __restrict__ attn_w,
                                                     const float* __restrict__ attn_b,
                                                     float* __restrict__ hb)
{
    int gid = blockIdx.x * 256 + threadIdx.x;          // 0..131071
    int kc = gid & 3;
    int b  = (gid >> 2) & 31;
    int h  = gid >> 7;
    const float* hp = hidden + b * HID + kc * 256;
    const float* wp = attn_w + (size_t)h * 3072 + kc * 256;
    float acc = 0.f;
    #pragma unroll 8
    for (int k = 0; k < 256; k += 4) {
        f32x4 hv = *(const f32x4*)(hp + k);
        f32x4 wv = *(const f32x4*)(wp + k);
        acc += hv[0]*wv[0] + hv[1]*wv[1] + hv[2]*wv[2] + hv[3]*wv[3];
    }
    acc += __shfl_xor(acc, 1);
    acc += __shfl_xor(acc, 2);
    if (kc == 0) hb[b * HID + h] = acc + attn_b[h];
}

// ---------------------------------------------------------------- fused GEMM + tanh + v-dot -> atomic logits
// A = enc (65536 x 2048 f32, contiguous rows, m = s*32+b), B = wbuf (1024 x 2048 bf16, K-major rows)
// 128x128 tile, BK=64, 4 waves (2x2). A: direct global->reg frags (f32->bf16 cvt), no LDS.
// B: global_load_lds dbuf, XOR-swizzled. Same-XCD grouping + circular-K stagger for A L2 reuse.
__global__ __launch_bounds__(256, 3)
void fused_attn_gemm(const float* __restrict__ enc,
                     const __bf16* __restrict__ wb,
                     const float* __restrict__ hb,
                     const float* __restrict__ v_w,
                     float* __restrict__ out)          // [32][2048] logits, atomically accumulated
{
    const int bid = blockIdx.x;
    const int x   = bid & 7;           // XCD id under round-robin dispatch
    const int j   = bid >> 3;          // 0..511 within XCD
    const int mt  = x * 64 + (j >> 3); // 64 contiguous M-tiles per XCD
    const int nc  = j & 7;             // 8 N-chunks of one mt are 8 consecutive same-XCD slots
    const int m0  = mt * 128;
    const int h0  = nc * 128;
    const int kt0 = nc * 4;            // circular-K stagger: sharers never race the same lines

    const int tid  = threadIdx.x;
    const int wid  = tid >> 6;
    const int lane = tid & 63;
    const int wr   = wid >> 1;
    const int wc   = wid & 1;
    const int l15  = lane & 15;
    const int g    = lane >> 4;

    __shared__ __attribute__((aligned(16))) __bf16 lB[2][128 * 64];

    f32x4 acc[4][4];
    #pragma unroll
    for (int i = 0; i < 4; ++i)
        #pragma unroll
        for (int jj = 0; jj < 4; ++jj)
            acc[i][jj] = (f32x4){0.f, 0.f, 0.f, 0.f};

    // ---- B staging via global_load_lds (linear LDS dest, inverse-swizzled global src)
    int bofs[4];
    const __bf16* bsrc[4];
    #pragma unroll
    for (int i = 0; i < 4; ++i) {
        int o  = (i * 256 + tid) * 16;   // byte offset in 16KiB tile
        int r  = o >> 7;                 // tile row 0..127
        int pc = (o >> 4) & 7;           // physical 16B chunk
        int c  = pc ^ (r & 7);           // logical chunk (XOR involution)
        bofs[i] = o >> 1;                // in shorts/__bf16
        bsrc[i] = wb + (size_t)(h0 + r) * KD + c * 8;
    }

    // ---- B fragment read offsets (row&7 == l15&7 for all frags)
    int rB[4];
    #pragma unroll
    for (int i = 0; i < 4; ++i)
        rB[i] = (wc * 64 + i * 16 + l15) * 64;
    const int sw0 = ((0 + g) ^ (l15 & 7)) * 8;
    const int sw1 = ((4 + g) ^ (l15 & 7)) * 8;

    // ---- A row bases: wave-row wr, frag-row mi*16+l15, lane k-offset g*8
    const float* aRow[4];
    #pragma unroll
    for (int i = 0; i < 4; ++i)
        aRow[i] = enc + (size_t)(m0 + wr * 64 + i * 16 + l15) * KD + g * 8;

    auto issueB = [&](int buf, int kt) {
        #pragma unroll
        for (int i = 0; i < 4; ++i) {
            __builtin_amdgcn_global_load_lds(
                (const __attribute__((address_space(1))) void*)(bsrc[i] + kt * 64),
                (__attribute__((address_space(3))) void*)&lB[buf][bofs[i]],
                16, 0, 0);
        }
    };
    auto compute = [&](int buf, int kt) {
        #pragma unroll
        for (int ks = 0; ks < 2; ++ks) {
            const int sw = ks ? sw1 : sw0;
            bf16x8 bfv[4];
            #pragma unroll
            for (int i = 0; i < 4; ++i) bfv[i] = *(const bf16x8*)&lB[buf][rB[i] + sw];
            bf16x8 af[4];
            #pragma unroll
            for (int mi = 0; mi < 4; ++mi) {
                const float* a0 = aRow[mi] + kt * 64 + ks * 32;
                f32x4 xv = *(const f32x4*)a0;
                f32x4 yv = *(const f32x4*)(a0 + 4);
                af[mi] = (bf16x8){ (__bf16)xv[0], (__bf16)xv[1], (__bf16)xv[2], (__bf16)xv[3],
                                   (__bf16)yv[0], (__bf16)yv[1], (__bf16)yv[2], (__bf16)yv[3] };
            }
            #pragma unroll
            for (int mi = 0; mi < 4; ++mi)
                #pragma unroll
                for (int ni = 0; ni < 4; ++ni)
                    acc[mi][ni] = __builtin_amdgcn_mfma_f32_16x16x32_bf16(
                        af[mi], bfv[ni], acc[mi][ni], 0, 0, 0);
        }
    };

    // prologue: stage B tile kt0
    issueB(0, kt0);
    __syncthreads();

    for (int t = 0; t < NK; ++t) {
        const int cur = t & 1;
        const int kt  = (kt0 + t) & (NK - 1);
        if (t + 1 < NK) issueB(cur ^ 1, (kt0 + t + 1) & (NK - 1));
        compute(cur, kt);
        __syncthreads();   // drains issueB's vmcnt; next iter reads buf cur^1
    }

    // ---- epilogue: energy = tanh(acc + hb[b][h]); logit += energy * v_w[h]
    float vw[4];
    #pragma unroll
    for (int ni = 0; ni < 4; ++ni)
        vw[ni] = v_w[h0 + wc * 64 + ni * 16 + l15];

    #pragma unroll
    for (int mi = 0; mi < 4; ++mi) {
        #pragma unroll
        for (int jj = 0; jj < 4; ++jj) {
            const int m = m0 + wr * 64 + mi * 16 + g * 4 + jj;  // C/D: row=(lane>>4)*4+reg
            const int b = m & 31;
            const int s = m >> 5;
            const float* hbrow = hb + b * HID + h0 + wc * 64;
            float sum = 0.f;
            #pragma unroll
            for (int ni = 0; ni < 4; ++ni) {
                float e = acc[mi][ni][jj] + hbrow[ni * 16 + l15]; // C/D: col=lane&15
                sum += tanhf(e) * vw[ni];
            }
            sum += __shfl_xor(sum, 1);
            sum += __shfl_xor(sum, 2);
            sum += __shfl_xor(sum, 4);
            sum += __shfl_xor(sum, 8);
            if (l15 == 0)
                atomicAdd(&out[b * SRC + s], sum);
        }
    }
}

// ---------------------------------------------------------------- in-place row softmax over s (row b is contiguous)
__global__ __launch_bounds__(256) void softmax_kernel(float* __restrict__ out)
{
    const int b = blockIdx.x;
    const int t = threadIdx.x;
    const int wid = t >> 6, lane = t & 63;
    __shared__ float redm[4], reds[4];

    float v[8];
    float mx = -3.4e38f;
    #pragma unroll
    for (int i = 0; i < 8; ++i) {
        v[i] = out[b * SRC + i * 256 + t];
        mx = fmaxf(mx, v[i]);
    }
    #pragma unroll
    for (int o = 1; o < 64; o <<= 1) mx = fmaxf(mx, __shfl_xor(mx, o));
    if (lane == 0) redm[wid] = mx;
    __syncthreads();
    mx = fmaxf(fmaxf(redm[0], redm[1]), fmaxf(redm[2], redm[3]));

    float sum = 0.f;
    #pragma unroll
    for (int i = 0; i < 8; ++i) { v[i] = expf(v[i] - mx); sum += v[i]; }
    #pragma unroll
    for (int o = 1; o < 64; o <<= 1) sum += __shfl_xor(sum, o);
    if (lane == 0) reds[wid] = sum;
    __syncthreads();
    sum = reds[0] + reds[1] + reds[2] + reds[3];

    const float inv = 1.f / sum;
    #pragma unroll
    for (int i = 0; i < 8; ++i) out[b * SRC + i * 256 + t] = v[i] * inv;
}

extern "C" void kernel_launch(void* const* d_in, const int* in_sizes, int n_in,
                              void* d_out, int out_size, void* d_ws, size_t ws_size,
                              hipStream_t stream)
{
    const float* hidden = (const float*)d_in[0];   // [32][1024]
    const float* enc    = (const float*)d_in[1];   // [2048][32][2048] == A[65536][2048]
    const float* attn_w = (const float*)d_in[2];   // [1024][3072]
    const float* attn_b = (const float*)d_in[3];   // [1024]
    const float* v_w    = (const float*)d_in[4];   // [1024]
    float* out = (float*)d_out;                    // [32][2048]

    __bf16* wbuf = (__bf16*)d_ws;                              // 4 MiB bf16 W_e
    float*  hb   = (float*)((char*)d_ws + (size_t)(4u << 20)); // 128 KiB hb

    prep_w_kernel<<<2048, 256, 0, stream>>>(attn_w, wbuf, out);
    prep_h_kernel<<<512, 256, 0, stream>>>(hidden, attn_w, attn_b, hb);
    fused_attn_gemm<<<4096, 256, 0, stream>>>(enc, wbuf, hb, v_w, out);
    softmax_kernel<<<32, 256, 0, stream>>>(out);
}